// Round 15
// baseline (65.877 us; speedup 1.0000x reference)
//
#include <hip/hip_runtime.h>
#include <stdint.h>

#define NA 250000
#define NC 80
#define KSEL 2048
#define CONF_THF 0.05f
#define IOU_THF 0.5f
#define HBINS 1024
#define HREP 16
#define HBASE 0x3D00u
#define EMAX 4096u
#define K5BLK 64

typedef unsigned int u32;
typedef unsigned long long u64;

// ---- workspace layout (bytes) ----
// No memset. hist fully overwritten by kH (direct store). scal/vbits/rank
// zeroed by k2 (single block) each call, stream-ordered before producers.
// scal: 1=above 2=kthKey 3=candCnt 4=maxCoordBits 5=edgeCnt
#define WS_HIST    0u          // 16 replicas x 1024 u32 (64KB)
#define WS_SCAL    65536u      // 16 u32
#define WS_VBITS   65600u      // 32 u64 valid bitmask per chunk
#define WS_RANK    65856u      // 4096 u32 rank accumulators
#define WS_MAXS    82240u      // 250000 f32
#define WS_LABELS  1082240u    // 250000 i32
#define WS_CAND    2082240u    // 4096 u32
#define WS_EDGES   2115008u    // 4096 u32 packed (i<<12)|j

// Correctly-rounded f32 sigmoid via double exp — ONLY for order-critical
// values (max_scores). Bit-identical to rounds 1-14 (proven to match numpy
// ranking on this input).
__device__ __forceinline__ float sigmoidf_(float x) {
  if (x >= 0.0f) {
    float ef = (float)exp(-(double)x);
    return 1.0f / (1.0f + ef);
  } else {
    float ef = (float)exp((double)x);
    return ef / (1.0f + ef);
  }
}

// Fast f32 sigmoid for value-only outputs (scores matrix; tolerance ~0.02).
__device__ __forceinline__ float sigmoid_fast(float x) {
  return 1.0f / (1.0f + __expf(-x));
}

__device__ __forceinline__ u64 cand_key(const float* __restrict__ maxs,
                                        const u32* __restrict__ cand, u32 i) {
  u32 a = cand[i];
  float s = maxs[a];
  u32 kb = (s > CONF_THF) ? __float_as_uint(s) : 0u;
  return ((u64)kb << 32) | (u64)(0xFFFFFFFFu - a);
}

// K1: pure stream — no LDS, no barrier, no atomics. 4 lanes/anchor with
// QUAD-INTERLEAVED float4 reads: lane p takes float4s {p,p+4,p+8,p+12,p+16}
// so each load instruction reads contiguous, fully-consumed 64B per quad.
// Class of (chunk i, elem q) on lane p = 16i+4p+q. Values bit-identical to
// rounds 1-14 (same multiset per anchor; explicit index tie-breaks).
__global__ void __launch_bounds__(256)
k1_scores(const float* __restrict__ cls, const float* __restrict__ cent,
          float* __restrict__ maxs, int* __restrict__ labels) {
  int t = blockIdx.x * 256 + threadIdx.x;
  int a = t >> 2, p = t & 3;
  if (a >= NA) return;
  const float4* row = (const float4*)(cls + (size_t)a * NC);
  float4 r0 = row[p], r1 = row[p + 4], r2 = row[p + 8],
         r3 = row[p + 12], r4 = row[p + 16];

  float lm = fmaxf(fmaxf(fmaxf(r0.x, r0.y), fmaxf(r0.z, r0.w)),
                   fmaxf(fmaxf(r1.x, r1.y), fmaxf(r1.z, r1.w)));
  lm = fmaxf(lm, fmaxf(fmaxf(r2.x, r2.y), fmaxf(r2.z, r2.w)));
  lm = fmaxf(lm, fmaxf(fmaxf(r3.x, r3.y), fmaxf(r3.z, r3.w)));
  lm = fmaxf(lm, fmaxf(fmaxf(r4.x, r4.y), fmaxf(r4.z, r4.w)));
  lm = fmaxf(lm, __shfl_xor(lm, 1));
  lm = fmaxf(lm, __shfl_xor(lm, 2));

  float cv = 0.0f;
  if (p == 0) cv = cent[a];
  float xin = (p == 0) ? cv : lm;
  float sg = 0.0f;
  if (p < 2) sg = sigmoidf_(xin);
  int qb = (threadIdx.x & 63) & ~3;
  float cp   = __shfl(sg, qb);       // sig(centerness)
  float slm  = __shfl(sg, qb + 1);   // sig(lmax)
  float smax = slm * cp;             // == max product (monotone, cp>=0)

  float thresh = lm - 2e-4f;
  int firstEq = 0x7fffffff;
  int wcnt = 0;
  {
    float vv[20] = {r0.x, r0.y, r0.z, r0.w, r1.x, r1.y, r1.z, r1.w,
                    r2.x, r2.y, r2.z, r2.w, r3.x, r3.y, r3.z, r3.w,
                    r4.x, r4.y, r4.z, r4.w};
#pragma unroll
    for (int j = 0; j < 20; j++) {
      int c = 16 * (j >> 2) + 4 * p + (j & 3);   // class index, new layout
      if (vv[j] == lm && c < firstEq) firstEq = c;
      wcnt += (vv[j] >= thresh) ? 1 : 0;
    }
#pragma unroll
    for (int off = 1; off <= 2; off <<= 1) {
      int oe = __shfl_xor(firstEq, off);
      int ow = __shfl_xor(wcnt, off);
      firstEq = (oe < firstEq) ? oe : firstEq;
      wcnt += ow;
    }
    float bs; int bc;
    if (wcnt <= 1) {
      bs = smax;
      bc = firstEq;
    } else {
      bs = -1.0f; bc = 0x7fffffff;
#pragma unroll
      for (int j = 0; j < 20; j++) {
        if (vv[j] >= thresh) {
          float s = sigmoidf_(vv[j]) * cp;
          int c = 16 * (j >> 2) + 4 * p + (j & 3);
          if (s > bs || (s == bs && c < bc)) { bs = s; bc = c; }
        }
      }
#pragma unroll
      for (int off = 1; off <= 2; off <<= 1) {
        float os = __shfl_xor(bs, off);
        int   oc = __shfl_xor(bc, off);
        if (os > bs || (os == bs && oc < bc)) { bs = os; bc = oc; }
      }
    }
    if (p == 0) {
      maxs[a] = bs;
      labels[a] = bc;
    }
  }
}

// KH: 16 blocks, block b owns replica b (LDS-private hist, direct store —
// full overwrite, no zeroing, no global atomics).
__global__ void __launch_bounds__(1024) kH_hist(const float* __restrict__ maxs,
                                                u32* __restrict__ hist) {
  __shared__ u32 lh[HBINS];
  for (int i = threadIdx.x; i < HBINS; i += 1024) lh[i] = 0u;
  __syncthreads();
  for (u32 a = blockIdx.x * 1024 + threadIdx.x; a < NA; a += 16 * 1024) {
    float s = maxs[a];
    if (s > CONF_THF) {
      u32 bin = (__float_as_uint(s) >> 16) - HBASE;
      atomicAdd(&lh[bin], 1u);
    }
  }
  __syncthreads();
  for (int i = threadIdx.x; i < HBINS; i += 1024)
    hist[(blockIdx.x << 10) + i] = lh[i];
}

// K2: zero scal/vbits/rank, then sum 16 replicas + suffix scan from top bin.
__global__ void __launch_bounds__(1024) k2_findbin(const u32* __restrict__ hist,
                                                   u32* __restrict__ scal,
                                                   u32* __restrict__ vbits32,
                                                   u32* __restrict__ rankArr) {
  __shared__ u32 sc[1024];
  int tid = threadIdx.x;
  if (tid < 16) scal[tid] = 0u;
  if (tid < 64) vbits32[tid] = 0u;
#pragma unroll
  for (int i = 0; i < 4; i++) rankArr[tid + i * 1024] = 0u;

  int bin = 1023 - tid;
  u32 c = 0;
#pragma unroll
  for (int r = 0; r < HREP; r++) c += hist[r * HBINS + bin];
  sc[tid] = c;
  for (int off = 1; off < 1024; off <<= 1) {
    __syncthreads();
    u32 t = (tid >= off) ? sc[tid - off] : 0u;
    __syncthreads();
    sc[tid] += t;
  }
  __syncthreads();
  u32 incl = sc[tid], excl = incl - c;
  if (incl >= KSEL && excl < KSEL) {
    scal[2] = ((u32)bin + HBASE) << 16;
    scal[1] = excl;
  }
  if (tid == 1023 && incl < KSEL) {
    scal[2] = 0u;
    scal[1] = incl;
  }
}

// K5: compact candidates with key >= kth. LDS-local list + ONE global
// atomicAdd per block. Set is deterministic; order irrelevant (placement
// is key-rank-determined).
__global__ void __launch_bounds__(1024) k5_compact(const float* __restrict__ maxs,
                                                   u32* __restrict__ scal,
                                                   u32* __restrict__ cand) {
  __shared__ u32 lcnt, lbase;
  __shared__ u32 llist[1024];
  if (threadIdx.x == 0) lcnt = 0u;
  __syncthreads();
  u32 kth = scal[2];
  for (u32 a = blockIdx.x * 1024 + threadIdx.x; a < NA; a += K5BLK * 1024) {
    float s = maxs[a];
    u32 key = (s > CONF_THF) ? __float_as_uint(s) : 0u;
    if (key >= kth && (key > 0u || a < KSEL)) {
      u32 p = atomicAdd(&lcnt, 1u);
      if (p < 1024u) llist[p] = a;
    }
  }
  __syncthreads();
  u32 n = lcnt < 1024u ? lcnt : 1024u;
  if (threadIdx.x == 0) lbase = atomicAdd(&scal[3], n);
  __syncthreads();
  u32 base = lbase;
  for (u32 j = threadIdx.x; j < n; j += 1024) {
    u32 pos = base + j;
    if (pos < 4096u) cand[pos] = llist[j];
  }
}

// K6a: distributed rank. Block (cgroup, seg): stage 256 keys of `seg` to
// LDS, each thread accumulates a partial rank, one atomicAdd into rankArr
// (per-lane distinct addresses -> no serialization).
__global__ void __launch_bounds__(256) k6a_rank(const float* __restrict__ maxs,
                                                const u32* __restrict__ cand,
                                                const u32* __restrict__ scal,
                                                u32* __restrict__ rankArr) {
  __shared__ u64 keys[256];
  u32 cnt = scal[3];
  u32 nn = cnt < 4096u ? cnt : 4096u;
  u32 seg0 = blockIdx.y * 256;
  u32 cg0 = blockIdx.x * 256;
  if (seg0 >= nn || cg0 >= nn) return;
  int tid = threadIdx.x;
  u32 si = seg0 + tid;
  keys[tid] = (si < nn) ? cand_key(maxs, cand, si) : 0ull;
  __syncthreads();
  u32 ci = cg0 + tid;
  if (ci >= nn) return;
  u64 mykey = cand_key(maxs, cand, ci);
  u32 lim = nn - seg0; if (lim > 256u) lim = 256u;
  u32 r = 0, i = 0;
  for (; i + 8 <= lim; i += 8) {
    r += (keys[i]     > mykey);
    r += (keys[i + 1] > mykey);
    r += (keys[i + 2] > mykey);
    r += (keys[i + 3] > mykey);
    r += (keys[i + 4] > mykey);
    r += (keys[i + 5] > mykey);
    r += (keys[i + 6] > mykey);
    r += (keys[i + 7] > mykey);
  }
  for (; i < lim; ++i) r += (keys[i] > mykey);
  if (r) atomicAdd(&rankArr[ci], r);
}

// K6b: scatter + FULL output gather (k7 folded in). Each thread with
// rank<KSEL writes boxes[rank], scores[rank][0..79], ms[rank], lab[rank],
// validBits, and contributes to max_coord (one atomicMax per wave).
__global__ void __launch_bounds__(256) k6b_scatter(const float* __restrict__ maxs,
                                                   const u32* __restrict__ cand,
                                                   u32* __restrict__ scal,
                                                   const u32* __restrict__ rankArr,
                                                   const float* __restrict__ bbox,
                                                   const float* __restrict__ cls,
                                                   const float* __restrict__ cent,
                                                   const int* __restrict__ labels,
                                                   u32* __restrict__ validBits32,
                                                   float* __restrict__ out) {
  float* out_boxes  = out;
  float* out_scores = out + KSEL * 4;
  float* out_ms     = out + KSEL * 4 + KSEL * NC;
  float* out_lab    = out_ms + KSEL;
  u32 cnt = scal[3];
  u32 nn = cnt < 4096u ? cnt : 4096u;
  u32 ci = blockIdx.x * 256 + threadIdx.x;
  float m = -1.0f;
  if (ci < nn) {
    u64 mykey = cand_key(maxs, cand, ci);
    u32 rank = rankArr[ci];
    if (rank < KSEL) {
      u32 a = 0xFFFFFFFFu - (u32)(mykey & 0xFFFFFFFFu);
      bool valid = (mykey >> 32) != 0ull;
      float4 b4 = ((const float4*)bbox)[a];
      ((float4*)out_boxes)[rank] = b4;
      out_ms[rank] = maxs[a];
      out_lab[rank] = (float)labels[a];
      if (valid) {
        atomicOr(&validBits32[rank >> 5], 1u << (rank & 31));
        m = fmaxf(fmaxf(b4.x, b4.y), fmaxf(b4.z, b4.w));
      }
      float cp = sigmoid_fast(cent[a]);
      const float4* crow = (const float4*)(cls + (size_t)a * NC);
      float4* srow = (float4*)(out_scores + (size_t)rank * NC);
#pragma unroll
      for (int j = 0; j < 20; j++) {
        float4 v = crow[j];
        float4 s;
        s.x = sigmoid_fast(v.x) * cp;
        s.y = sigmoid_fast(v.y) * cp;
        s.z = sigmoid_fast(v.z) * cp;
        s.w = sigmoid_fast(v.w) * cp;
        srow[j] = s;
      }
    }
  }
#pragma unroll
  for (int off = 1; off < 64; off <<= 1) m = fmaxf(m, __shfl_xor(m, off));
  if ((threadIdx.x & 63) == 0 && m >= 0.0f)
    atomicMax((int*)&scal[4], __float_as_int(m));   // coords >= 0
}

// K8: triangular grid (528 blocks) of 64x64 IoU tiles -> sparse edge list.
__global__ void __launch_bounds__(64) k8_edges(const float* __restrict__ out,
                                               u32* __restrict__ scal,
                                               u32* __restrict__ edges) {
  __shared__ float cx1[64], cy1[64], cx2[64], cy2[64], car[64];
  // linear bid -> (bx >= by) upper-triangle pair
  int bid = blockIdx.x;
  int bx = (int)((sqrtf(8.0f * bid + 1.0f) - 1.0f) * 0.5f);
  while ((bx + 1) * (bx + 2) / 2 <= bid) bx++;
  while (bx * (bx + 1) / 2 > bid) bx--;
  int by = bid - bx * (bx + 1) / 2;   // by in [0, bx]
  const float* boxes = out;
  const float* lab = out + KSEL * 4 + KSEL * NC + KSEL;
  float mc1 = __int_as_float(*(const int*)&scal[4]) + 1.0f;
  int t = threadIdx.x;
  int j0 = bx * 64;
  int j = j0 + t;
  {
    float off = lab[j] * mc1;
    float x1 = boxes[j * 4 + 0] + off, y1 = boxes[j * 4 + 1] + off;
    float x2 = boxes[j * 4 + 2] + off, y2 = boxes[j * 4 + 3] + off;
    cx1[t] = x1; cy1[t] = y1; cx2[t] = x2; cy2[t] = y2;
    car[t] = (x2 - x1) * (y2 - y1);
  }
  __syncthreads();
  int i = by * 64 + t;
  float off = lab[i] * mc1;
  float x1 = boxes[i * 4 + 0] + off, y1 = boxes[i * 4 + 1] + off;
  float x2 = boxes[i * 4 + 2] + off, y2 = boxes[i * 4 + 3] + off;
  float ar = (x2 - x1) * (y2 - y1);
  for (int jj = 0; jj < 64; jj++) {
    float ix = fminf(x2, cx2[jj]) - fmaxf(x1, cx1[jj]);
    float iy = fminf(y2, cy2[jj]) - fmaxf(y1, cy1[jj]);
    float inter = fmaxf(ix, 0.0f) * fmaxf(iy, 0.0f);
    float uni = ar + car[jj] - inter;
    float iou = inter / fmaxf(uni, 1e-9f);
    int jidx = j0 + jj;
    if (iou > IOU_THF && i < jidx) {
      u32 pos = atomicAdd(&scal[5], 1u);
      if (pos < EMAX) edges[pos] = ((u32)i << 12) | (u32)jidx;
    }
  }
}

// K9: greedy NMS as Jacobi fixed-point on the sparse suppression DAG.
__global__ void k9_nms(const u32* __restrict__ edges, const u32* __restrict__ scal,
                       const u64* __restrict__ validBits,
                       float* __restrict__ out_keep) {
  __shared__ u32 aliveLds[64];
  __shared__ u32 supLds[64];
  int lane = threadIdx.x;       // 64 threads = one wave
  u32 E = scal[5]; if (E > EMAX) E = EMAX;
  u64 vw = (lane < 32) ? validBits[lane] : 0ull;
  u64 alive = vw;
  for (int it = 0; it < 2048; ++it) {
    if (lane < 32) {
      aliveLds[2 * lane]     = (u32)alive;
      aliveLds[2 * lane + 1] = (u32)(alive >> 32);
    }
    supLds[lane] = 0u;
    __syncthreads();
    for (u32 e = lane; e < E; e += 64) {
      u32 p = edges[e];
      u32 i = p >> 12, j = p & 0xFFFu;
      if ((aliveLds[i >> 5] >> (i & 31)) & 1u)
        atomicOr(&supLds[j >> 5], 1u << (j & 31));
    }
    __syncthreads();
    u64 na = alive;
    if (lane < 32) {
      u64 sup = (u64)supLds[2 * lane] | ((u64)supLds[2 * lane + 1] << 32);
      na = vw & ~sup;
    }
    u64 anych = __ballot(na != alive);
    alive = na;
    __syncthreads();
    if (anych == 0ull) break;
  }
  if (lane < 32) {
    aliveLds[2 * lane]     = (u32)alive;
    aliveLds[2 * lane + 1] = (u32)(alive >> 32);
  }
  __syncthreads();
#pragma unroll
  for (int t = 0; t < 32; ++t) {
    int idx = t * 64 + lane;
    out_keep[idx] = ((aliveLds[idx >> 5] >> (idx & 31)) & 1u) ? 1.0f : 0.0f;
  }
}

extern "C" void kernel_launch(void* const* d_in, const int* in_sizes, int n_in,
                              void* d_out, int out_size, void* d_ws, size_t ws_size,
                              hipStream_t stream) {
  const float* cls  = (const float*)d_in[0];
  const float* bbox = (const float*)d_in[1];
  const float* cent = (const float*)d_in[2];
  float* out = (float*)d_out;
  char* ws = (char*)d_ws;
  u32* hist      = (u32*)(ws + WS_HIST);
  u32* scal      = (u32*)(ws + WS_SCAL);
  u32* vbits32   = (u32*)(ws + WS_VBITS);
  u32* rankArr   = (u32*)(ws + WS_RANK);
  float* maxs    = (float*)(ws + WS_MAXS);
  int* labels    = (int*)(ws + WS_LABELS);
  u32* cand      = (u32*)(ws + WS_CAND);
  u32* edges     = (u32*)(ws + WS_EDGES);

  (void)in_sizes; (void)n_in; (void)out_size; (void)ws_size;

  k1_scores<<<(NA * 4 + 255) / 256, 256, 0, stream>>>(cls, cent, maxs, labels);
  kH_hist<<<16, 1024, 0, stream>>>(maxs, hist);
  k2_findbin<<<1, 1024, 0, stream>>>(hist, scal, vbits32, rankArr);
  k5_compact<<<K5BLK, 1024, 0, stream>>>(maxs, scal, cand);
  k6a_rank<<<dim3(16, 16), 256, 0, stream>>>(maxs, cand, scal, rankArr);
  k6b_scatter<<<16, 256, 0, stream>>>(maxs, cand, scal, rankArr, bbox, cls, cent,
                                      labels, vbits32, out);
  k8_edges<<<528, 64, 0, stream>>>(out, scal, edges);
  k9_nms<<<1, 64, 0, stream>>>(edges, scal, (const u64*)vbits32,
                               out + KSEL * 4 + KSEL * NC + KSEL * 2);
}

// Round 16
// 60.259 us; speedup vs baseline: 1.0932x; 1.0932x over previous
//
#include <hip/hip_runtime.h>
#include <stdint.h>

#define NA 250000
#define NC 80
#define KSEL 2048
#define CONF_THF 0.05f
#define IOU_THF 0.5f
#define HBINS 1024
#define HREP 16
#define HBASE 0x3D00u
#define EMAX 4096u
#define K5BLK 64

typedef unsigned int u32;
typedef unsigned long long u64;

// ---- workspace layout (bytes) ----
// No memset. hist fully overwritten by kH (direct store); kH block 0 also
// zeroes scal/vbits/rank (consumers are stream-ordered after kH).
// k5 recomputes kth per-block from hist (no k2 node).
// scal: 3=candCnt 4=maxCoordBits 5=edgeCnt
#define WS_HIST    0u          // 16 replicas x 1024 u32 (64KB)
#define WS_SCAL    65536u      // 16 u32
#define WS_VBITS   65600u      // 32 u64 valid bitmask per chunk
#define WS_RANK    65856u      // 4096 u32 rank accumulators
#define WS_MAXS    82240u      // 250000 f32
#define WS_LABELS  1082240u    // 250000 i32
#define WS_CAND    2082240u    // 4096 u32
#define WS_SIDX    2098624u    // 2048 u32
#define WS_VALID   2106816u    // 2048 u32
#define WS_EDGES   2115008u    // 4096 u32 packed (i<<12)|j

// Correctly-rounded f32 sigmoid via double exp — ONLY for order-critical
// values (max_scores). Bit-identical to rounds 1-15 (proven to match numpy
// ranking on this input).
__device__ __forceinline__ float sigmoidf_(float x) {
  if (x >= 0.0f) {
    float ef = (float)exp(-(double)x);
    return 1.0f / (1.0f + ef);
  } else {
    float ef = (float)exp((double)x);
    return ef / (1.0f + ef);
  }
}

// Fast f32 sigmoid for value-only outputs (scores matrix; tolerance ~0.02).
__device__ __forceinline__ float sigmoid_fast(float x) {
  return 1.0f / (1.0f + __expf(-x));
}

__device__ __forceinline__ u64 cand_key(const float* __restrict__ maxs,
                                        const u32* __restrict__ cand, u32 i) {
  u32 a = cand[i];
  float s = maxs[a];
  u32 kb = (s > CONF_THF) ? __float_as_uint(s) : 0u;
  return ((u64)kb << 32) | (u64)(0xFFFFFFFFu - a);
}

// K1: pure stream — no LDS, no barrier, no atomics. 4 lanes/anchor, each
// lane reads its own 80B (r14 layout). One exp-chain per wave.
__global__ void __launch_bounds__(256)
k1_scores(const float* __restrict__ cls, const float* __restrict__ cent,
          float* __restrict__ maxs, int* __restrict__ labels) {
  int t = blockIdx.x * 256 + threadIdx.x;
  int a = t >> 2, p = t & 3;
  if (a >= NA) return;
  const float4* row = (const float4*)(cls + (size_t)a * NC) + p * 5;
  float4 r0 = row[0], r1 = row[1], r2 = row[2], r3 = row[3], r4 = row[4];

  float lm = fmaxf(fmaxf(fmaxf(r0.x, r0.y), fmaxf(r0.z, r0.w)),
                   fmaxf(fmaxf(r1.x, r1.y), fmaxf(r1.z, r1.w)));
  lm = fmaxf(lm, fmaxf(fmaxf(r2.x, r2.y), fmaxf(r2.z, r2.w)));
  lm = fmaxf(lm, fmaxf(fmaxf(r3.x, r3.y), fmaxf(r3.z, r3.w)));
  lm = fmaxf(lm, fmaxf(fmaxf(r4.x, r4.y), fmaxf(r4.z, r4.w)));
  lm = fmaxf(lm, __shfl_xor(lm, 1));
  lm = fmaxf(lm, __shfl_xor(lm, 2));

  float cv = 0.0f;
  if (p == 0) cv = cent[a];
  float xin = (p == 0) ? cv : lm;
  float sg = 0.0f;
  if (p < 2) sg = sigmoidf_(xin);
  int qb = (threadIdx.x & 63) & ~3;
  float cp   = __shfl(sg, qb);       // sig(centerness)
  float slm  = __shfl(sg, qb + 1);   // sig(lmax)
  float smax = slm * cp;             // == max product (monotone, cp>=0)

  float thresh = lm - 2e-4f;
  int firstEq = 0x7fffffff;
  int wcnt = 0;
  {
    float vv[20] = {r0.x, r0.y, r0.z, r0.w, r1.x, r1.y, r1.z, r1.w,
                    r2.x, r2.y, r2.z, r2.w, r3.x, r3.y, r3.z, r3.w,
                    r4.x, r4.y, r4.z, r4.w};
#pragma unroll
    for (int q = 0; q < 20; q++) {
      int c = p * 20 + q;
      if (vv[q] == lm && c < firstEq) firstEq = c;
      wcnt += (vv[q] >= thresh) ? 1 : 0;
    }
#pragma unroll
    for (int off = 1; off <= 2; off <<= 1) {
      int oe = __shfl_xor(firstEq, off);
      int ow = __shfl_xor(wcnt, off);
      firstEq = (oe < firstEq) ? oe : firstEq;
      wcnt += ow;
    }
    float bs; int bc;
    if (wcnt <= 1) {
      bs = smax;
      bc = firstEq;
    } else {
      bs = -1.0f; bc = 0x7fffffff;
#pragma unroll
      for (int q = 0; q < 20; q++) {
        if (vv[q] >= thresh) {
          float s = sigmoidf_(vv[q]) * cp;
          int c = p * 20 + q;
          if (s > bs || (s == bs && c < bc)) { bs = s; bc = c; }
        }
      }
#pragma unroll
      for (int off = 1; off <= 2; off <<= 1) {
        float os = __shfl_xor(bs, off);
        int   oc = __shfl_xor(bc, off);
        if (os > bs || (os == bs && oc < bc)) { bs = os; bc = oc; }
      }
    }
    if (p == 0) {
      maxs[a] = bs;
      labels[a] = bc;
    }
  }
}

// KH: 16 blocks, block b owns replica b (LDS-private hist, direct store —
// full overwrite, no zeroing, no global atomics). Block 0 additionally
// zeroes scal/vbits/rank (all consumers are stream-ordered after kH).
__global__ void __launch_bounds__(1024) kH_hist(const float* __restrict__ maxs,
                                                u32* __restrict__ hist,
                                                u32* __restrict__ scal,
                                                u32* __restrict__ vbits32,
                                                u32* __restrict__ rankArr) {
  __shared__ u32 lh[HBINS];
  int tid = threadIdx.x;
  if (blockIdx.x == 0) {
    if (tid < 16) scal[tid] = 0u;
    if (tid < 64) vbits32[tid] = 0u;
#pragma unroll
    for (int i = 0; i < 4; i++) rankArr[tid + i * 1024] = 0u;
  }
  for (int i = tid; i < HBINS; i += 1024) lh[i] = 0u;
  __syncthreads();
  for (u32 a = blockIdx.x * 1024 + tid; a < NA; a += 16 * 1024) {
    float s = maxs[a];
    if (s > CONF_THF) {
      u32 bin = (__float_as_uint(s) >> 16) - HBASE;
      atomicAdd(&lh[bin], 1u);
    }
  }
  __syncthreads();
  for (int i = tid; i < HBINS; i += 1024)
    hist[(blockIdx.x << 10) + i] = lh[i];
}

// K5: per-block kth recompute (16-replica sum + LDS suffix scan; identical
// and deterministic in every block, hist is L2-hot) + LDS-local compaction
// with ONE global atomicAdd per block.
__global__ void __launch_bounds__(1024) k5_compact(const float* __restrict__ maxs,
                                                   const u32* __restrict__ hist,
                                                   u32* __restrict__ scal,
                                                   u32* __restrict__ cand) {
  __shared__ u32 sc[1024];
  __shared__ u32 llist[1024];
  __shared__ u32 lcnt, lbase, kthS;
  int tid = threadIdx.x;
  // ---- suffix scan from top bin (same as old k2, per block) ----
  int bin = 1023 - tid;
  u32 c = 0;
#pragma unroll
  for (int r = 0; r < HREP; r++) c += hist[r * HBINS + bin];
  sc[tid] = c;
  for (int off = 1; off < 1024; off <<= 1) {
    __syncthreads();
    u32 t2 = (tid >= off) ? sc[tid - off] : 0u;
    __syncthreads();
    sc[tid] += t2;
  }
  __syncthreads();
  u32 incl = sc[tid], excl = incl - c;
  if (incl >= KSEL && excl < KSEL) kthS = ((u32)bin + HBASE) << 16;
  if (tid == 1023 && incl < KSEL) kthS = 0u;   // fewer than K total
  if (tid == 0) lcnt = 0u;
  __syncthreads();
  u32 kth = kthS;
  // ---- compaction ----
  for (u32 a = blockIdx.x * 1024 + tid; a < NA; a += K5BLK * 1024) {
    float s = maxs[a];
    u32 key = (s > CONF_THF) ? __float_as_uint(s) : 0u;
    if (key >= kth && (key > 0u || a < KSEL)) {
      u32 p = atomicAdd(&lcnt, 1u);
      if (p < 1024u) llist[p] = a;
    }
  }
  __syncthreads();
  u32 n = lcnt < 1024u ? lcnt : 1024u;
  if (tid == 0) lbase = atomicAdd(&scal[3], n);
  __syncthreads();
  u32 base = lbase;
  for (u32 j = tid; j < n; j += 1024) {
    u32 pos = base + j;
    if (pos < 4096u) cand[pos] = llist[j];
  }
}

// K6a: distributed rank. Block (cgroup, seg): stage 256 keys of `seg` to
// LDS, each thread accumulates a partial rank, one atomicAdd into rankArr
// (per-lane distinct addresses -> no serialization).
__global__ void __launch_bounds__(256) k6a_rank(const float* __restrict__ maxs,
                                                const u32* __restrict__ cand,
                                                const u32* __restrict__ scal,
                                                u32* __restrict__ rankArr) {
  __shared__ u64 keys[256];
  u32 cnt = scal[3];
  u32 nn = cnt < 4096u ? cnt : 4096u;
  u32 seg0 = blockIdx.y * 256;
  u32 cg0 = blockIdx.x * 256;
  if (seg0 >= nn || cg0 >= nn) return;
  int tid = threadIdx.x;
  u32 si = seg0 + tid;
  keys[tid] = (si < nn) ? cand_key(maxs, cand, si) : 0ull;
  __syncthreads();
  u32 ci = cg0 + tid;
  if (ci >= nn) return;
  u64 mykey = cand_key(maxs, cand, ci);
  u32 lim = nn - seg0; if (lim > 256u) lim = 256u;
  u32 r = 0, i = 0;
  for (; i + 8 <= lim; i += 8) {
    r += (keys[i]     > mykey);
    r += (keys[i + 1] > mykey);
    r += (keys[i + 2] > mykey);
    r += (keys[i + 3] > mykey);
    r += (keys[i + 4] > mykey);
    r += (keys[i + 5] > mykey);
    r += (keys[i + 6] > mykey);
    r += (keys[i + 7] > mykey);
  }
  for (; i < lim; ++i) r += (keys[i] > mykey);
  if (r) atomicAdd(&rankArr[ci], r);
}

// K6b: scatter candidates by final rank + max_coord via wave-level reduce
// (one atomicMax per wave).
__global__ void __launch_bounds__(256) k6b_scatter(const float* __restrict__ maxs,
                                                   const u32* __restrict__ cand,
                                                   const u32* __restrict__ scal,
                                                   const u32* __restrict__ rankArr,
                                                   const float* __restrict__ bbox,
                                                   u32* __restrict__ sidx,
                                                   u32* __restrict__ validArr,
                                                   u32* __restrict__ validBits32,
                                                   u32* __restrict__ scalW) {
  u32 cnt = scal[3];
  u32 nn = cnt < 4096u ? cnt : 4096u;
  u32 ci = blockIdx.x * 256 + threadIdx.x;
  float m = -1.0f;
  if (ci < nn) {
    u64 mykey = cand_key(maxs, cand, ci);
    u32 rank = rankArr[ci];
    if (rank < KSEL) {
      u32 a = 0xFFFFFFFFu - (u32)(mykey & 0xFFFFFFFFu);
      bool valid = (mykey >> 32) != 0ull;
      sidx[rank] = a;
      validArr[rank] = valid ? 1u : 0u;
      if (valid) {
        atomicOr(&validBits32[rank >> 5], 1u << (rank & 31));
        float4 b4 = ((const float4*)bbox)[a];
        m = fmaxf(fmaxf(b4.x, b4.y), fmaxf(b4.z, b4.w));
      }
    }
  }
#pragma unroll
  for (int off = 1; off < 64; off <<= 1) m = fmaxf(m, __shfl_xor(m, off));
  if ((threadIdx.x & 63) == 0 && m >= 0.0f)
    atomicMax((int*)&scalW[4], __float_as_int(m));   // coords >= 0
}

// K7: gather outputs (no atomics).
__global__ void k7_gather(const float* __restrict__ cls, const float* __restrict__ cent,
                          const float* __restrict__ bbox, const float* __restrict__ maxs,
                          const int* __restrict__ labels, const u32* __restrict__ sidx,
                          float* __restrict__ out) {
  int r = blockIdx.x;
  int tid = threadIdx.x;
  u32 a = sidx[r];
  float* out_boxes  = out;
  float* out_scores = out + KSEL * 4;
  float* out_ms     = out + KSEL * 4 + KSEL * NC;
  float* out_lab    = out_ms + KSEL;
  if (tid < NC) {
    float cp = sigmoid_fast(cent[a]);
    float s = sigmoid_fast(cls[(size_t)a * NC + tid]) * cp;
    out_scores[(size_t)r * NC + tid] = s;
  } else if (tid < NC + 4) {
    int q = tid - NC;
    out_boxes[r * 4 + q] = bbox[(size_t)a * 4 + q];
  } else if (tid == NC + 4) {
    out_ms[r] = maxs[a];
  } else if (tid == NC + 5) {
    out_lab[r] = (float)labels[a];
  }
}

// K8: 64x64 IoU tiles (upper triangle only) -> sparse edge list (i<j).
__global__ void k8_edges(const float* __restrict__ out, u32* __restrict__ scal,
                         u32* __restrict__ edges) {
  if (blockIdx.x < blockIdx.y) return;
  __shared__ float cx1[64], cy1[64], cx2[64], cy2[64], car[64];
  const float* boxes = out;
  const float* lab = out + KSEL * 4 + KSEL * NC + KSEL;
  float mc1 = __int_as_float(*(const int*)&scal[4]) + 1.0f;
  int t = threadIdx.x;
  int j0 = blockIdx.x * 64;
  int j = j0 + t;
  {
    float off = lab[j] * mc1;
    float x1 = boxes[j * 4 + 0] + off, y1 = boxes[j * 4 + 1] + off;
    float x2 = boxes[j * 4 + 2] + off, y2 = boxes[j * 4 + 3] + off;
    cx1[t] = x1; cy1[t] = y1; cx2[t] = x2; cy2[t] = y2;
    car[t] = (x2 - x1) * (y2 - y1);
  }
  __syncthreads();
  int i = blockIdx.y * 64 + t;
  float off = lab[i] * mc1;
  float x1 = boxes[i * 4 + 0] + off, y1 = boxes[i * 4 + 1] + off;
  float x2 = boxes[i * 4 + 2] + off, y2 = boxes[i * 4 + 3] + off;
  float ar = (x2 - x1) * (y2 - y1);
  for (int jj = 0; jj < 64; jj++) {
    float ix = fminf(x2, cx2[jj]) - fmaxf(x1, cx1[jj]);
    float iy = fminf(y2, cy2[jj]) - fmaxf(y1, cy1[jj]);
    float inter = fmaxf(ix, 0.0f) * fmaxf(iy, 0.0f);
    float uni = ar + car[jj] - inter;
    float iou = inter / fmaxf(uni, 1e-9f);
    int jidx = j0 + jj;
    if (iou > IOU_THF && i < jidx) {
      u32 pos = atomicAdd(&scal[5], 1u);
      if (pos < EMAX) edges[pos] = ((u32)i << 12) | (u32)jidx;
    }
  }
}

// K9: greedy NMS as Jacobi fixed-point on the sparse suppression DAG.
__global__ void k9_nms(const u32* __restrict__ edges, const u32* __restrict__ scal,
                       const u64* __restrict__ validBits,
                       float* __restrict__ out_keep) {
  __shared__ u32 aliveLds[64];
  __shared__ u32 supLds[64];
  int lane = threadIdx.x;       // 64 threads = one wave
  u32 E = scal[5]; if (E > EMAX) E = EMAX;
  u64 vw = (lane < 32) ? validBits[lane] : 0ull;
  u64 alive = vw;
  for (int it = 0; it < 2048; ++it) {
    if (lane < 32) {
      aliveLds[2 * lane]     = (u32)alive;
      aliveLds[2 * lane + 1] = (u32)(alive >> 32);
    }
    supLds[lane] = 0u;
    __syncthreads();
    for (u32 e = lane; e < E; e += 64) {
      u32 p = edges[e];
      u32 i = p >> 12, j = p & 0xFFFu;
      if ((aliveLds[i >> 5] >> (i & 31)) & 1u)
        atomicOr(&supLds[j >> 5], 1u << (j & 31));
    }
    __syncthreads();
    u64 na = alive;
    if (lane < 32) {
      u64 sup = (u64)supLds[2 * lane] | ((u64)supLds[2 * lane + 1] << 32);
      na = vw & ~sup;
    }
    u64 anych = __ballot(na != alive);
    alive = na;
    __syncthreads();
    if (anych == 0ull) break;
  }
  if (lane < 32) {
    aliveLds[2 * lane]     = (u32)alive;
    aliveLds[2 * lane + 1] = (u32)(alive >> 32);
  }
  __syncthreads();
#pragma unroll
  for (int t = 0; t < 32; ++t) {
    int idx = t * 64 + lane;
    out_keep[idx] = ((aliveLds[idx >> 5] >> (idx & 31)) & 1u) ? 1.0f : 0.0f;
  }
}

extern "C" void kernel_launch(void* const* d_in, const int* in_sizes, int n_in,
                              void* d_out, int out_size, void* d_ws, size_t ws_size,
                              hipStream_t stream) {
  const float* cls  = (const float*)d_in[0];
  const float* bbox = (const float*)d_in[1];
  const float* cent = (const float*)d_in[2];
  float* out = (float*)d_out;
  char* ws = (char*)d_ws;
  u32* hist      = (u32*)(ws + WS_HIST);
  u32* scal      = (u32*)(ws + WS_SCAL);
  u32* vbits32   = (u32*)(ws + WS_VBITS);
  u32* rankArr   = (u32*)(ws + WS_RANK);
  float* maxs    = (float*)(ws + WS_MAXS);
  int* labels    = (int*)(ws + WS_LABELS);
  u32* cand      = (u32*)(ws + WS_CAND);
  u32* sidx      = (u32*)(ws + WS_SIDX);
  u32* validArr  = (u32*)(ws + WS_VALID);
  u32* edges     = (u32*)(ws + WS_EDGES);

  (void)in_sizes; (void)n_in; (void)out_size; (void)ws_size;

  k1_scores<<<(NA * 4 + 255) / 256, 256, 0, stream>>>(cls, cent, maxs, labels);
  kH_hist<<<16, 1024, 0, stream>>>(maxs, hist, scal, vbits32, rankArr);
  k5_compact<<<K5BLK, 1024, 0, stream>>>(maxs, hist, scal, cand);
  k6a_rank<<<dim3(16, 16), 256, 0, stream>>>(maxs, cand, scal, rankArr);
  k6b_scatter<<<16, 256, 0, stream>>>(maxs, cand, scal, rankArr, bbox, sidx, validArr, vbits32, scal);
  k7_gather<<<KSEL, 128, 0, stream>>>(cls, cent, bbox, maxs, labels, sidx, out);
  k8_edges<<<dim3(32, 32), 64, 0, stream>>>(out, scal, edges);
  k9_nms<<<1, 64, 0, stream>>>(edges, scal, (const u64*)vbits32, out + KSEL * 4 + KSEL * NC + KSEL * 2);
}

// Round 17
// 60.215 us; speedup vs baseline: 1.0940x; 1.0007x over previous
//
#include <hip/hip_runtime.h>
#include <stdint.h>

#define NA 250000
#define NC 80
#define KSEL 2048
#define CONF_THF 0.05f
#define IOU_THF 0.5f
#define HBINS 1024
#define HREP 16
#define HBASE 0x3D00u
#define EMAX 4096u
#define K5BLK 64

typedef unsigned int u32;
typedef unsigned long long u64;

// ---- workspace layout (bytes) ----
// No memset. hist fully overwritten by kH (direct store); kH block 0 also
// zeroes scal/vbits/rank (consumers are stream-ordered after kH).
// k5 recomputes kth per-block from hist (no k2 node).
// scal: 3=candCnt 4=maxCoordBits 5=edgeCnt
#define WS_HIST    0u          // 16 replicas x 1024 u32 (64KB)
#define WS_SCAL    65536u      // 16 u32
#define WS_VBITS   65600u      // 32 u64 valid bitmask per chunk
#define WS_RANK    65856u      // 4096 u32 rank accumulators
#define WS_MAXS    82240u      // 250000 f32
#define WS_LABELS  1082240u    // 250000 i32
#define WS_CAND    2082240u    // 4096 u32
#define WS_SIDX    2098624u    // 2048 u32
#define WS_VALID   2106816u    // 2048 u32
#define WS_EDGES   2115008u    // 4096 u32 packed (i<<12)|j

// Correctly-rounded f32 sigmoid via double exp — ONLY for order-critical
// values (max_scores). Bit-identical to rounds 1-16 (proven to match numpy
// ranking on this input).
__device__ __forceinline__ float sigmoidf_(float x) {
  if (x >= 0.0f) {
    float ef = (float)exp(-(double)x);
    return 1.0f / (1.0f + ef);
  } else {
    float ef = (float)exp((double)x);
    return ef / (1.0f + ef);
  }
}

// Fast f32 sigmoid for value-only outputs (scores matrix; tolerance ~0.02).
__device__ __forceinline__ float sigmoid_fast(float x) {
  return 1.0f / (1.0f + __expf(-x));
}

__device__ __forceinline__ u64 cand_key(const float* __restrict__ maxs,
                                        const u32* __restrict__ cand, u32 i) {
  u32 a = cand[i];
  float s = maxs[a];
  u32 kb = (s > CONF_THF) ? __float_as_uint(s) : 0u;
  return ((u64)kb << 32) | (u64)(0xFFFFFFFFu - a);
}

// K1: pure stream — no LDS, no barrier, no atomics. 4 lanes/anchor with
// QUAD-INTERLEAVED float4 reads: lane p takes float4s {p,p+4,p+8,p+12,p+16}
// of its anchor's 80 floats, so consecutive 4 lanes read contiguous 64B and
// each VMEM instruction touches only 16 cache lines (coalescing optimum)
// instead of ~64. Class of (chunk j>>2, elem j&3) on lane p = 16(j>>2)+4p+(j&3).
// Values bit-identical to rounds 1-16 (same per-anchor multiset; explicit
// index tie-breaks).
__global__ void __launch_bounds__(256)
k1_scores(const float* __restrict__ cls, const float* __restrict__ cent,
          float* __restrict__ maxs, int* __restrict__ labels) {
  int t = blockIdx.x * 256 + threadIdx.x;
  int a = t >> 2, p = t & 3;
  if (a >= NA) return;
  const float4* row = (const float4*)(cls + (size_t)a * NC);
  float4 r0 = row[p], r1 = row[p + 4], r2 = row[p + 8],
         r3 = row[p + 12], r4 = row[p + 16];

  float lm = fmaxf(fmaxf(fmaxf(r0.x, r0.y), fmaxf(r0.z, r0.w)),
                   fmaxf(fmaxf(r1.x, r1.y), fmaxf(r1.z, r1.w)));
  lm = fmaxf(lm, fmaxf(fmaxf(r2.x, r2.y), fmaxf(r2.z, r2.w)));
  lm = fmaxf(lm, fmaxf(fmaxf(r3.x, r3.y), fmaxf(r3.z, r3.w)));
  lm = fmaxf(lm, fmaxf(fmaxf(r4.x, r4.y), fmaxf(r4.z, r4.w)));
  lm = fmaxf(lm, __shfl_xor(lm, 1));
  lm = fmaxf(lm, __shfl_xor(lm, 2));

  float cv = 0.0f;
  if (p == 0) cv = cent[a];
  float xin = (p == 0) ? cv : lm;
  float sg = 0.0f;
  if (p < 2) sg = sigmoidf_(xin);
  int qb = (threadIdx.x & 63) & ~3;
  float cp   = __shfl(sg, qb);       // sig(centerness)
  float slm  = __shfl(sg, qb + 1);   // sig(lmax)
  float smax = slm * cp;             // == max product (monotone, cp>=0)

  float thresh = lm - 2e-4f;
  int firstEq = 0x7fffffff;
  int wcnt = 0;
  {
    float vv[20] = {r0.x, r0.y, r0.z, r0.w, r1.x, r1.y, r1.z, r1.w,
                    r2.x, r2.y, r2.z, r2.w, r3.x, r3.y, r3.z, r3.w,
                    r4.x, r4.y, r4.z, r4.w};
#pragma unroll
    for (int j = 0; j < 20; j++) {
      int c = 16 * (j >> 2) + 4 * p + (j & 3);   // class index, interleaved layout
      if (vv[j] == lm && c < firstEq) firstEq = c;
      wcnt += (vv[j] >= thresh) ? 1 : 0;
    }
#pragma unroll
    for (int off = 1; off <= 2; off <<= 1) {
      int oe = __shfl_xor(firstEq, off);
      int ow = __shfl_xor(wcnt, off);
      firstEq = (oe < firstEq) ? oe : firstEq;
      wcnt += ow;
    }
    float bs; int bc;
    if (wcnt <= 1) {
      bs = smax;
      bc = firstEq;
    } else {
      bs = -1.0f; bc = 0x7fffffff;
#pragma unroll
      for (int j = 0; j < 20; j++) {
        if (vv[j] >= thresh) {
          float s = sigmoidf_(vv[j]) * cp;
          int c = 16 * (j >> 2) + 4 * p + (j & 3);
          if (s > bs || (s == bs && c < bc)) { bs = s; bc = c; }
        }
      }
#pragma unroll
      for (int off = 1; off <= 2; off <<= 1) {
        float os = __shfl_xor(bs, off);
        int   oc = __shfl_xor(bc, off);
        if (os > bs || (os == bs && oc < bc)) { bs = os; bc = oc; }
      }
    }
    if (p == 0) {
      maxs[a] = bs;
      labels[a] = bc;
    }
  }
}

// KH: 16 blocks, block b owns replica b (LDS-private hist, direct store —
// full overwrite, no zeroing, no global atomics). Block 0 additionally
// zeroes scal/vbits/rank (all consumers are stream-ordered after kH).
__global__ void __launch_bounds__(1024) kH_hist(const float* __restrict__ maxs,
                                                u32* __restrict__ hist,
                                                u32* __restrict__ scal,
                                                u32* __restrict__ vbits32,
                                                u32* __restrict__ rankArr) {
  __shared__ u32 lh[HBINS];
  int tid = threadIdx.x;
  if (blockIdx.x == 0) {
    if (tid < 16) scal[tid] = 0u;
    if (tid < 64) vbits32[tid] = 0u;
#pragma unroll
    for (int i = 0; i < 4; i++) rankArr[tid + i * 1024] = 0u;
  }
  for (int i = tid; i < HBINS; i += 1024) lh[i] = 0u;
  __syncthreads();
  for (u32 a = blockIdx.x * 1024 + tid; a < NA; a += 16 * 1024) {
    float s = maxs[a];
    if (s > CONF_THF) {
      u32 bin = (__float_as_uint(s) >> 16) - HBASE;
      atomicAdd(&lh[bin], 1u);
    }
  }
  __syncthreads();
  for (int i = tid; i < HBINS; i += 1024)
    hist[(blockIdx.x << 10) + i] = lh[i];
}

// K5: per-block kth recompute (16-replica sum + LDS suffix scan; identical
// and deterministic in every block, hist is L2-hot) + LDS-local compaction
// with ONE global atomicAdd per block.
__global__ void __launch_bounds__(1024) k5_compact(const float* __restrict__ maxs,
                                                   const u32* __restrict__ hist,
                                                   u32* __restrict__ scal,
                                                   u32* __restrict__ cand) {
  __shared__ u32 sc[1024];
  __shared__ u32 llist[1024];
  __shared__ u32 lcnt, lbase, kthS;
  int tid = threadIdx.x;
  // ---- suffix scan from top bin (same as old k2, per block) ----
  int bin = 1023 - tid;
  u32 c = 0;
#pragma unroll
  for (int r = 0; r < HREP; r++) c += hist[r * HBINS + bin];
  sc[tid] = c;
  for (int off = 1; off < 1024; off <<= 1) {
    __syncthreads();
    u32 t2 = (tid >= off) ? sc[tid - off] : 0u;
    __syncthreads();
    sc[tid] += t2;
  }
  __syncthreads();
  u32 incl = sc[tid], excl = incl - c;
  if (incl >= KSEL && excl < KSEL) kthS = ((u32)bin + HBASE) << 16;
  if (tid == 1023 && incl < KSEL) kthS = 0u;   // fewer than K total
  if (tid == 0) lcnt = 0u;
  __syncthreads();
  u32 kth = kthS;
  // ---- compaction ----
  for (u32 a = blockIdx.x * 1024 + tid; a < NA; a += K5BLK * 1024) {
    float s = maxs[a];
    u32 key = (s > CONF_THF) ? __float_as_uint(s) : 0u;
    if (key >= kth && (key > 0u || a < KSEL)) {
      u32 p = atomicAdd(&lcnt, 1u);
      if (p < 1024u) llist[p] = a;
    }
  }
  __syncthreads();
  u32 n = lcnt < 1024u ? lcnt : 1024u;
  if (tid == 0) lbase = atomicAdd(&scal[3], n);
  __syncthreads();
  u32 base = lbase;
  for (u32 j = tid; j < n; j += 1024) {
    u32 pos = base + j;
    if (pos < 4096u) cand[pos] = llist[j];
  }
}

// K6a: distributed rank. Block (cgroup, seg): stage 256 keys of `seg` to
// LDS, each thread accumulates a partial rank, one atomicAdd into rankArr
// (per-lane distinct addresses -> no serialization).
__global__ void __launch_bounds__(256) k6a_rank(const float* __restrict__ maxs,
                                                const u32* __restrict__ cand,
                                                const u32* __restrict__ scal,
                                                u32* __restrict__ rankArr) {
  __shared__ u64 keys[256];
  u32 cnt = scal[3];
  u32 nn = cnt < 4096u ? cnt : 4096u;
  u32 seg0 = blockIdx.y * 256;
  u32 cg0 = blockIdx.x * 256;
  if (seg0 >= nn || cg0 >= nn) return;
  int tid = threadIdx.x;
  u32 si = seg0 + tid;
  keys[tid] = (si < nn) ? cand_key(maxs, cand, si) : 0ull;
  __syncthreads();
  u32 ci = cg0 + tid;
  if (ci >= nn) return;
  u64 mykey = cand_key(maxs, cand, ci);
  u32 lim = nn - seg0; if (lim > 256u) lim = 256u;
  u32 r = 0, i = 0;
  for (; i + 8 <= lim; i += 8) {
    r += (keys[i]     > mykey);
    r += (keys[i + 1] > mykey);
    r += (keys[i + 2] > mykey);
    r += (keys[i + 3] > mykey);
    r += (keys[i + 4] > mykey);
    r += (keys[i + 5] > mykey);
    r += (keys[i + 6] > mykey);
    r += (keys[i + 7] > mykey);
  }
  for (; i < lim; ++i) r += (keys[i] > mykey);
  if (r) atomicAdd(&rankArr[ci], r);
}

// K6b: scatter candidates by final rank + max_coord via wave-level reduce
// (one atomicMax per wave).
__global__ void __launch_bounds__(256) k6b_scatter(const float* __restrict__ maxs,
                                                   const u32* __restrict__ cand,
                                                   const u32* __restrict__ scal,
                                                   const u32* __restrict__ rankArr,
                                                   const float* __restrict__ bbox,
                                                   u32* __restrict__ sidx,
                                                   u32* __restrict__ validArr,
                                                   u32* __restrict__ validBits32,
                                                   u32* __restrict__ scalW) {
  u32 cnt = scal[3];
  u32 nn = cnt < 4096u ? cnt : 4096u;
  u32 ci = blockIdx.x * 256 + threadIdx.x;
  float m = -1.0f;
  if (ci < nn) {
    u64 mykey = cand_key(maxs, cand, ci);
    u32 rank = rankArr[ci];
    if (rank < KSEL) {
      u32 a = 0xFFFFFFFFu - (u32)(mykey & 0xFFFFFFFFu);
      bool valid = (mykey >> 32) != 0ull;
      sidx[rank] = a;
      validArr[rank] = valid ? 1u : 0u;
      if (valid) {
        atomicOr(&validBits32[rank >> 5], 1u << (rank & 31));
        float4 b4 = ((const float4*)bbox)[a];
        m = fmaxf(fmaxf(b4.x, b4.y), fmaxf(b4.z, b4.w));
      }
    }
  }
#pragma unroll
  for (int off = 1; off < 64; off <<= 1) m = fmaxf(m, __shfl_xor(m, off));
  if ((threadIdx.x & 63) == 0 && m >= 0.0f)
    atomicMax((int*)&scalW[4], __float_as_int(m));   // coords >= 0
}

// K7: gather outputs (no atomics).
__global__ void k7_gather(const float* __restrict__ cls, const float* __restrict__ cent,
                          const float* __restrict__ bbox, const float* __restrict__ maxs,
                          const int* __restrict__ labels, const u32* __restrict__ sidx,
                          float* __restrict__ out) {
  int r = blockIdx.x;
  int tid = threadIdx.x;
  u32 a = sidx[r];
  float* out_boxes  = out;
  float* out_scores = out + KSEL * 4;
  float* out_ms     = out + KSEL * 4 + KSEL * NC;
  float* out_lab    = out_ms + KSEL;
  if (tid < NC) {
    float cp = sigmoid_fast(cent[a]);
    float s = sigmoid_fast(cls[(size_t)a * NC + tid]) * cp;
    out_scores[(size_t)r * NC + tid] = s;
  } else if (tid < NC + 4) {
    int q = tid - NC;
    out_boxes[r * 4 + q] = bbox[(size_t)a * 4 + q];
  } else if (tid == NC + 4) {
    out_ms[r] = maxs[a];
  } else if (tid == NC + 5) {
    out_lab[r] = (float)labels[a];
  }
}

// K8: 64x64 IoU tiles (upper triangle only) -> sparse edge list (i<j).
__global__ void k8_edges(const float* __restrict__ out, u32* __restrict__ scal,
                         u32* __restrict__ edges) {
  if (blockIdx.x < blockIdx.y) return;
  __shared__ float cx1[64], cy1[64], cx2[64], cy2[64], car[64];
  const float* boxes = out;
  const float* lab = out + KSEL * 4 + KSEL * NC + KSEL;
  float mc1 = __int_as_float(*(const int*)&scal[4]) + 1.0f;
  int t = threadIdx.x;
  int j0 = blockIdx.x * 64;
  int j = j0 + t;
  {
    float off = lab[j] * mc1;
    float x1 = boxes[j * 4 + 0] + off, y1 = boxes[j * 4 + 1] + off;
    float x2 = boxes[j * 4 + 2] + off, y2 = boxes[j * 4 + 3] + off;
    cx1[t] = x1; cy1[t] = y1; cx2[t] = x2; cy2[t] = y2;
    car[t] = (x2 - x1) * (y2 - y1);
  }
  __syncthreads();
  int i = blockIdx.y * 64 + t;
  float off = lab[i] * mc1;
  float x1 = boxes[i * 4 + 0] + off, y1 = boxes[i * 4 + 1] + off;
  float x2 = boxes[i * 4 + 2] + off, y2 = boxes[i * 4 + 3] + off;
  float ar = (x2 - x1) * (y2 - y1);
  for (int jj = 0; jj < 64; jj++) {
    float ix = fminf(x2, cx2[jj]) - fmaxf(x1, cx1[jj]);
    float iy = fminf(y2, cy2[jj]) - fmaxf(y1, cy1[jj]);
    float inter = fmaxf(ix, 0.0f) * fmaxf(iy, 0.0f);
    float uni = ar + car[jj] - inter;
    float iou = inter / fmaxf(uni, 1e-9f);
    int jidx = j0 + jj;
    if (iou > IOU_THF && i < jidx) {
      u32 pos = atomicAdd(&scal[5], 1u);
      if (pos < EMAX) edges[pos] = ((u32)i << 12) | (u32)jidx;
    }
  }
}

// K9: greedy NMS as Jacobi fixed-point on the sparse suppression DAG.
__global__ void k9_nms(const u32* __restrict__ edges, const u32* __restrict__ scal,
                       const u64* __restrict__ validBits,
                       float* __restrict__ out_keep) {
  __shared__ u32 aliveLds[64];
  __shared__ u32 supLds[64];
  int lane = threadIdx.x;       // 64 threads = one wave
  u32 E = scal[5]; if (E > EMAX) E = EMAX;
  u64 vw = (lane < 32) ? validBits[lane] : 0ull;
  u64 alive = vw;
  for (int it = 0; it < 2048; ++it) {
    if (lane < 32) {
      aliveLds[2 * lane]     = (u32)alive;
      aliveLds[2 * lane + 1] = (u32)(alive >> 32);
    }
    supLds[lane] = 0u;
    __syncthreads();
    for (u32 e = lane; e < E; e += 64) {
      u32 p = edges[e];
      u32 i = p >> 12, j = p & 0xFFFu;
      if ((aliveLds[i >> 5] >> (i & 31)) & 1u)
        atomicOr(&supLds[j >> 5], 1u << (j & 31));
    }
    __syncthreads();
    u64 na = alive;
    if (lane < 32) {
      u64 sup = (u64)supLds[2 * lane] | ((u64)supLds[2 * lane + 1] << 32);
      na = vw & ~sup;
    }
    u64 anych = __ballot(na != alive);
    alive = na;
    __syncthreads();
    if (anych == 0ull) break;
  }
  if (lane < 32) {
    aliveLds[2 * lane]     = (u32)alive;
    aliveLds[2 * lane + 1] = (u32)(alive >> 32);
  }
  __syncthreads();
#pragma unroll
  for (int t = 0; t < 32; ++t) {
    int idx = t * 64 + lane;
    out_keep[idx] = ((aliveLds[idx >> 5] >> (idx & 31)) & 1u) ? 1.0f : 0.0f;
  }
}

extern "C" void kernel_launch(void* const* d_in, const int* in_sizes, int n_in,
                              void* d_out, int out_size, void* d_ws, size_t ws_size,
                              hipStream_t stream) {
  const float* cls  = (const float*)d_in[0];
  const float* bbox = (const float*)d_in[1];
  const float* cent = (const float*)d_in[2];
  float* out = (float*)d_out;
  char* ws = (char*)d_ws;
  u32* hist      = (u32*)(ws + WS_HIST);
  u32* scal      = (u32*)(ws + WS_SCAL);
  u32* vbits32   = (u32*)(ws + WS_VBITS);
  u32* rankArr   = (u32*)(ws + WS_RANK);
  float* maxs    = (float*)(ws + WS_MAXS);
  int* labels    = (int*)(ws + WS_LABELS);
  u32* cand      = (u32*)(ws + WS_CAND);
  u32* sidx      = (u32*)(ws + WS_SIDX);
  u32* validArr  = (u32*)(ws + WS_VALID);
  u32* edges     = (u32*)(ws + WS_EDGES);

  (void)in_sizes; (void)n_in; (void)out_size; (void)ws_size;

  k1_scores<<<(NA * 4 + 255) / 256, 256, 0, stream>>>(cls, cent, maxs, labels);
  kH_hist<<<16, 1024, 0, stream>>>(maxs, hist, scal, vbits32, rankArr);
  k5_compact<<<K5BLK, 1024, 0, stream>>>(maxs, hist, scal, cand);
  k6a_rank<<<dim3(16, 16), 256, 0, stream>>>(maxs, cand, scal, rankArr);
  k6b_scatter<<<16, 256, 0, stream>>>(maxs, cand, scal, rankArr, bbox, sidx, validArr, vbits32, scal);
  k7_gather<<<KSEL, 128, 0, stream>>>(cls, cent, bbox, maxs, labels, sidx, out);
  k8_edges<<<dim3(32, 32), 64, 0, stream>>>(out, scal, edges);
  k9_nms<<<1, 64, 0, stream>>>(edges, scal, (const u64*)vbits32, out + KSEL * 4 + KSEL * NC + KSEL * 2);
}